// Round 6
// baseline (1647.891 us; speedup 1.0000x reference)
//
#include <hip/hip_runtime.h>
#include <hip/hip_bf16.h>
#include <cmath>

// Problem constants
#define BB 64
#define NN 512
#define NBS 8
#define EE 2048
#define HH 128
#define LL 3
#define KK 4
#define AF 82
#define BF 6
#define SLAB 4194304   // B*N*H floats

typedef __attribute__((ext_vector_type(8))) short bf16x8;
typedef __attribute__((ext_vector_type(4))) float f32x4;

__device__ __forceinline__ float gelu1(float x){ return 0.5f*x*(1.f+erff(x*0.7071067811865475f)); }
__device__ __forceinline__ float sig1(float x){ return 1.f/(1.f+expf(-x)); }
__device__ __forceinline__ short f2bs(float x){ __hip_bfloat16 b=__float2bfloat16(x); return *reinterpret_cast<short*>(&b); }
__device__ __forceinline__ float bs2f(short s){ unsigned u = ((unsigned)(unsigned short)s) << 16; union{unsigned u; float f;} c; c.u=u; return c.f; }
__device__ __forceinline__ void split2(float v, short& hi, short& lo){ hi = f2bs(v); lo = f2bs(v - bs2f(hi)); }
__device__ __forceinline__ void split8(float4 a, float4 b, bf16x8& h, bf16x8& l){
    float av[8] = {a.x,a.y,a.z,a.w,b.x,b.y,b.z,b.w};
    #pragma unroll
    for (int j = 0; j < 8; ++j) { short hh, ll; split2(av[j], hh, ll); h[j]=hh; l[j]=ll; }
}

#define MFMA3(ACC, AH, AL, BH, BL) \
    ACC = __builtin_amdgcn_mfma_f32_16x16x32_bf16(AH, BH, ACC, 0,0,0); \
    ACC = __builtin_amdgcn_mfma_f32_16x16x32_bf16(AL, BH, ACC, 0,0,0); \
    ACC = __builtin_amdgcn_mfma_f32_16x16x32_bf16(AH, BL, ACC, 0,0,0);

// ---------------------------------------------------------------------------
// vchain: fused u2 -> support -> fu -> sv -> wzm1 z-gate -> GRU, row-local.
// Block = 256 thr (4 waves), 64 rows; wave = 16 rows; grid = B*N/64 = 512.
// Intermediates live in per-wave LDS (16x132).
// ---------------------------------------------------------------------------
__global__ __launch_bounds__(256) void vchain(
    const short* __restrict__ nlh, const short* __restrict__ nll,
    float* __restrict__ vf, short* __restrict__ vfh, short* __restrict__ vfl,
    const float* __restrict__ h0,
    const short* __restrict__ wu2, const float* __restrict__ u2b,
    const short* __restrict__ wfu, const float* __restrict__ fub,
    const short* __restrict__ wzm, const float* __restrict__ zmb,
    const short* __restrict__ wih, const short* __restrict__ whh,
    const float* __restrict__ bih, const float* __restrict__ bhh,
    const float* __restrict__ t2, const float* __restrict__ m2m,
    float theta)
{
    __shared__ float buf[4][16*132];
    const int t = threadIdx.x;
    const int lane = t & 63, wv = t >> 6;
    const int quad = lane >> 4, ml = lane & 15;
    const int base = blockIdx.x*64 + wv*16;
    const int arow = base + ml;
    const int bb = base >> 9;
    float* Bf = buf[wv];

    f32x4 acc[8];
    #pragma unroll
    for (int i = 0; i < 8; ++i) acc[i] = (f32x4){0.f,0.f,0.f,0.f};

    // ---- stage A: hi = concat(nl, vf) @ u2  (K=256)
    #pragma unroll
    for (int kc = 0; kc < 8; ++kc) {
        const int kq = kc*32 + quad*8;
        bf16x8 ah, al;
        if (kq < 128) {
            ah = *(const bf16x8*)(nlh + (size_t)arow*128 + kq);
            al = *(const bf16x8*)(nll + (size_t)arow*128 + kq);
        } else {
            ah = *(const bf16x8*)(vfh + (size_t)arow*128 + kq - 128);
            al = *(const bf16x8*)(vfl + (size_t)arow*128 + kq - 128);
        }
        #pragma unroll
        for (int nt = 0; nt < 8; ++nt) {
            const short* bp = wu2 + (size_t)(nt*16+ml)*256 + kq;
            bf16x8 bh = *(const bf16x8*)bp;
            bf16x8 bl = *(const bf16x8*)(bp + 98304);
            MFMA3(acc[nt], ah, al, bh, bl);
        }
    }
    // support = 0.9*hi + 0.1*h0
    f32x4 supC[8];
    #pragma unroll
    for (int nt = 0; nt < 8; ++nt) {
        int col = nt*16 + ml; float bj = u2b[col];
        #pragma unroll
        for (int r = 0; r < 4; ++r) {
            int row = base + quad*4 + r;
            supC[nt][r] = 0.9f*(acc[nt][r] + bj) + 0.1f*h0[(size_t)row*128 + col];
        }
    }
    #pragma unroll
    for (int nt = 0; nt < 8; ++nt)
        #pragma unroll
        for (int r = 0; r < 4; ++r)
            Bf[(quad*4+r)*132 + nt*16 + ml] = supC[nt][r];
    __syncthreads();

    // ---- stage B: sv = theta*(support@fu + b) + (1-theta)*support
    #pragma unroll
    for (int i = 0; i < 8; ++i) acc[i] = (f32x4){0.f,0.f,0.f,0.f};
    #pragma unroll
    for (int kc = 0; kc < 4; ++kc) {
        const int kq = kc*32 + quad*8;
        float4 v0 = *(const float4*)&Bf[ml*132 + kq];
        float4 v1 = *(const float4*)&Bf[ml*132 + kq + 4];
        bf16x8 ah, al; split8(v0, v1, ah, al);
        #pragma unroll
        for (int nt = 0; nt < 8; ++nt) {
            const short* bp = wfu + (size_t)(nt*16+ml)*128 + kq;
            bf16x8 bh = *(const bf16x8*)bp;
            bf16x8 bl = *(const bf16x8*)(bp + 49152);
            MFMA3(acc[nt], ah, al, bh, bl);
        }
    }
    f32x4 svC[8];
    #pragma unroll
    for (int nt = 0; nt < 8; ++nt) {
        int col = nt*16 + ml; float bj = fub[col];
        #pragma unroll
        for (int r = 0; r < 4; ++r)
            svC[nt][r] = theta*(acc[nt][r] + bj) + (1.f-theta)*supC[nt][r];
    }
    __syncthreads();
    #pragma unroll
    for (int nt = 0; nt < 8; ++nt)
        #pragma unroll
        for (int r = 0; r < 4; ++r)
            Bf[(quad*4+r)*132 + nt*16 + ml] = svC[nt][r];
    __syncthreads();

    // ---- stage C: z = sig(sv@wzm1 + b + t2[b]); hidden = (1-z)*sv + z*m2m[b]
    #pragma unroll
    for (int i = 0; i < 8; ++i) acc[i] = (f32x4){0.f,0.f,0.f,0.f};
    #pragma unroll
    for (int kc = 0; kc < 4; ++kc) {
        const int kq = kc*32 + quad*8;
        float4 v0 = *(const float4*)&Bf[ml*132 + kq];
        float4 v1 = *(const float4*)&Bf[ml*132 + kq + 4];
        bf16x8 ah, al; split8(v0, v1, ah, al);
        #pragma unroll
        for (int nt = 0; nt < 8; ++nt) {
            const short* bp = wzm + (size_t)(nt*16+ml)*128 + kq;
            bf16x8 bh = *(const bf16x8*)bp;
            bf16x8 bl = *(const bf16x8*)(bp + 49152);
            MFMA3(acc[nt], ah, al, bh, bl);
        }
    }
    f32x4 hidC[8];
    #pragma unroll
    for (int nt = 0; nt < 8; ++nt) {
        int col = nt*16 + ml;
        float bj = zmb[col];
        float t2v = t2[(size_t)bb*128 + col];
        float m2v = m2m[(size_t)bb*128 + col];
        #pragma unroll
        for (int r = 0; r < 4; ++r) {
            float z = sig1(acc[nt][r] + bj + t2v);
            hidC[nt][r] = (1.f-z)*svC[nt][r] + z*m2v;
        }
    }
    __syncthreads();
    #pragma unroll
    for (int nt = 0; nt < 8; ++nt)
        #pragma unroll
        for (int r = 0; r < 4; ++r)
            Bf[(quad*4+r)*132 + nt*16 + ml] = hidC[nt][r];
    __syncthreads();

    // ---- stage D: GRU (gate-by-gate)
    bf16x8 va_h[4], va_l[4];
    #pragma unroll
    for (int kc = 0; kc < 4; ++kc) {
        const int kq = kc*32 + quad*8;
        va_h[kc] = *(const bf16x8*)(vfh + (size_t)arow*128 + kq);
        va_l[kc] = *(const bf16x8*)(vfl + (size_t)arow*128 + kq);
    }
    f32x4 rg[8], zg[8];
    #pragma unroll
    for (int g = 0; g < 3; ++g) {
        f32x4 gi[8], gh[8];
        #pragma unroll
        for (int i = 0; i < 8; ++i) { gi[i] = (f32x4){0.f,0.f,0.f,0.f}; gh[i] = (f32x4){0.f,0.f,0.f,0.f}; }
        #pragma unroll
        for (int kc = 0; kc < 4; ++kc) {
            const int kq = kc*32 + quad*8;
            float4 v0 = *(const float4*)&Bf[ml*132 + kq];
            float4 v1 = *(const float4*)&Bf[ml*132 + kq + 4];
            bf16x8 xh, xl; split8(v0, v1, xh, xl);
            #pragma unroll
            for (int nt = 0; nt < 8; ++nt) {
                const size_t widx = (size_t)(g*128 + nt*16 + ml)*128 + kq;
                const short* bpi = wih + widx;
                bf16x8 bh1 = *(const bf16x8*)bpi;
                bf16x8 bl1 = *(const bf16x8*)(bpi + 49152);
                MFMA3(gi[nt], xh, xl, bh1, bl1);
                const short* bpj = whh + widx;
                bf16x8 bh2 = *(const bf16x8*)bpj;
                bf16x8 bl2 = *(const bf16x8*)(bpj + 49152);
                MFMA3(gh[nt], va_h[kc], va_l[kc], bh2, bl2);
            }
        }
        if (g == 0) {
            #pragma unroll
            for (int nt = 0; nt < 8; ++nt) {
                int col = nt*16 + ml; float b1 = bih[col], b2 = bhh[col];
                #pragma unroll
                for (int r = 0; r < 4; ++r) rg[nt][r] = sig1(gi[nt][r] + b1 + gh[nt][r] + b2);
            }
        } else if (g == 1) {
            #pragma unroll
            for (int nt = 0; nt < 8; ++nt) {
                int col = nt*16 + ml; float b1 = bih[128+col], b2 = bhh[128+col];
                #pragma unroll
                for (int r = 0; r < 4; ++r) zg[nt][r] = sig1(gi[nt][r] + b1 + gh[nt][r] + b2);
            }
        } else {
            #pragma unroll
            for (int nt = 0; nt < 8; ++nt) {
                int col = nt*16 + ml; float b1 = bih[256+col], b2 = bhh[256+col];
                #pragma unroll
                for (int r = 0; r < 4; ++r) {
                    int row = base + quad*4 + r;
                    size_t off = (size_t)row*128 + col;
                    float n = tanhf(gi[nt][r] + b1 + rg[nt][r]*(gh[nt][r] + b2));
                    float hv = vf[off];
                    float o = (1.f-zg[nt][r])*n + zg[nt][r]*hv;
                    vf[off] = o;
                    short hh2, ll2; split2(o, hh2, ll2);
                    vfh[off] = hh2; vfl[off] = ll2;
                }
            }
        }
    }
}

// ---------------------------------------------------------------------------
// mvscore: score[b,k,n] = sum_d tanh(vf@wvm[k]+b)[d]*master[b,d]*wbmm[k,d] + wbb[k]
// A-frags cached in registers across all 4 heads. Block=128 rows, grid=256.
// ---------------------------------------------------------------------------
__global__ __launch_bounds__(256) void mvscore_kernel(
    const short* __restrict__ vfh, const short* __restrict__ vfl,
    const short* __restrict__ WT, const float* __restrict__ bias,
    const float* __restrict__ master,
    const float* __restrict__ wbw, const float* __restrict__ wbb,
    float* __restrict__ score)
{
    const int t = threadIdx.x;
    const int lane = t & 63, wv = t >> 6;
    const int quad = lane >> 4, ml = lane & 15;
    const int b = blockIdx.x >> 2;
    const int r0 = blockIdx.x*128 + wv*32 + ml;
    const int r1 = r0 + 16;

    bf16x8 a0h[4], a0l[4], a1h[4], a1l[4];
    #pragma unroll
    for (int kc = 0; kc < 4; ++kc) {
        const int kq = kc*32 + quad*8;
        a0h[kc] = *(const bf16x8*)(vfh + (size_t)r0*128 + kq);
        a0l[kc] = *(const bf16x8*)(vfl + (size_t)r0*128 + kq);
        a1h[kc] = *(const bf16x8*)(vfh + (size_t)r1*128 + kq);
        a1l[kc] = *(const bf16x8*)(vfl + (size_t)r1*128 + kq);
    }

    for (int k = 0; k < 4; ++k) {
        f32x4 acc[16];
        #pragma unroll
        for (int i = 0; i < 16; ++i) acc[i] = (f32x4){0.f,0.f,0.f,0.f};
        const short* wcol = WT + (size_t)k*16384 + (size_t)ml*128;
        #pragma unroll
        for (int kc = 0; kc < 4; ++kc) {
            const int kq = kc*32 + quad*8;
            #pragma unroll
            for (int nt = 0; nt < 8; ++nt) {
                const short* bp = wcol + (size_t)nt*16*128 + kq;
                bf16x8 bh = *(const bf16x8*)bp;
                bf16x8 bl = *(const bf16x8*)(bp + 196608);
                MFMA3(acc[nt],   a0h[kc], a0l[kc], bh, bl);
                MFMA3(acc[8+nt], a1h[kc], a1l[kc], bh, bl);
            }
        }
        float wv8[8], bj8[8];
        #pragma unroll
        for (int nt = 0; nt < 8; ++nt) {
            int col = nt*16 + ml;
            wv8[nt] = master[(size_t)b*128 + col] * wbw[(size_t)k*128 + col];
            bj8[nt] = bias[(size_t)k*128 + col];
        }
        float kb = wbb[k];
        #pragma unroll
        for (int mt = 0; mt < 2; ++mt) {
            #pragma unroll
            for (int r = 0; r < 4; ++r) {
                float s = 0.f;
                #pragma unroll
                for (int nt = 0; nt < 8; ++nt)
                    s += tanhf(acc[mt*8+nt][r] + bj8[nt]) * wv8[nt];
                s += __shfl_xor(s, 1); s += __shfl_xor(s, 2);
                s += __shfl_xor(s, 4); s += __shfl_xor(s, 8);
                if (ml == 0) {
                    int nloc = (blockIdx.x & 3)*128 + wv*32 + mt*16 + quad*4 + r;
                    score[((size_t)(b*KK + k))*NN + nloc] = s + kb;
                }
            }
        }
    }
}

// ---------------------------------------------------------------------------
// attctx: softmax(score row) -> satt + ctx = att @ vf. One block per (b,k).
// ---------------------------------------------------------------------------
__global__ __launch_bounds__(256) void attctx_kernel(
    const float* __restrict__ score, const float* __restrict__ vm,
    const float* __restrict__ vf,
    float* __restrict__ satt, float* __restrict__ ctx)
{
    __shared__ float red[256];
    __shared__ float att[512];
    const int t = threadIdx.x;
    const int bk = blockIdx.x, b = bk >> 2;
    float v0 = score[(size_t)bk*NN + t], v1 = score[(size_t)bk*NN + 256 + t];
    red[t] = fmaxf(v0, v1); __syncthreads();
    for (int s = 128; s; s >>= 1) { if (t < s) red[t] = fmaxf(red[t], red[t+s]); __syncthreads(); }
    float mx = red[0]; __syncthreads();
    float e0 = expf(v0 - mx) * vm[b*NN + t];
    float e1 = expf(v1 - mx) * vm[b*NN + t + 256];
    red[t] = e0 + e1; __syncthreads();
    for (int s = 128; s; s >>= 1) { if (t < s) red[t] += red[t+s]; __syncthreads(); }
    float sum = red[0];
    float inv = 1.f / (sum + 1e-6f);
    att[t] = e0*inv; att[t+256] = e1*inv;
    if (t == 0) satt[bk] = sum*inv;
    __syncthreads();
    const int d = t & 127, h = t >> 7;
    float acc = 0.f;
    const float* V = vf + (size_t)b*NN*HH;
    #pragma unroll 4
    for (int n = h*256; n < h*256 + 256; ++n) acc += att[n]*V[(size_t)n*HH + d];
    red[t] = acc; __syncthreads();
    if (t < 128) ctx[(size_t)bk*HH + t] = red[t] + red[t+128];
}

// ---------------------------------------------------------------------------
// u1: nl = segsum_s gelu(concat(vf[aa], e[ba]) @ u1 + b)*nbm -> bf16 planes
// Block 128 rows of B*N*NBS; grid = 2048.
// ---------------------------------------------------------------------------
__global__ __launch_bounds__(256) void u1_kernel(
    const short* __restrict__ vfh, const short* __restrict__ vfl,
    const short* __restrict__ eh, const short* __restrict__ el,
    const short* __restrict__ WT, const float* __restrict__ bias,
    const int* __restrict__ aadj, const int* __restrict__ badj,
    const float* __restrict__ nbm,
    short* __restrict__ nlh, short* __restrict__ nll)
{
    __shared__ float red[4][16][132];
    const int t = threadIdx.x;
    const int lane = t & 63, wv = t >> 6;
    const int quad = lane >> 4, ml = lane & 15;
    const int m0 = blockIdx.x*128 + wv*32;
    const int r0 = m0 + ml, r1 = m0 + 16 + ml;
    const int ga0 = aadj[r0], ga1 = aadj[r1];
    const int gb0 = badj[r0], gb1 = badj[r1];

    f32x4 acc[16];
    #pragma unroll
    for (int i = 0; i < 16; ++i) acc[i] = (f32x4){0.f,0.f,0.f,0.f};
    const short* wcol = WT + (size_t)ml*160;

    #pragma unroll
    for (int kc = 0; kc < 5; ++kc) {
        const int kq = kc*32 + quad*8;
        bf16x8 a0h, a0l, a1h, a1l;
        if (kq < 128) {
            a0h = *(const bf16x8*)(vfh + (size_t)ga0*128 + kq);
            a0l = *(const bf16x8*)(vfl + (size_t)ga0*128 + kq);
            a1h = *(const bf16x8*)(vfh + (size_t)ga1*128 + kq);
            a1l = *(const bf16x8*)(vfl + (size_t)ga1*128 + kq);
        } else if (kq == 128) {
            a0h = *(const bf16x8*)(eh + (size_t)gb0*8);
            a0l = *(const bf16x8*)(el + (size_t)gb0*8);
            a1h = *(const bf16x8*)(eh + (size_t)gb1*8);
            a1l = *(const bf16x8*)(el + (size_t)gb1*8);
        } else {
            #pragma unroll
            for (int j = 0; j < 8; ++j) { a0h[j]=0; a0l[j]=0; a1h[j]=0; a1l[j]=0; }
        }
        #pragma unroll
        for (int nt = 0; nt < 8; ++nt) {
            const short* bp = wcol + (size_t)nt*16*160 + kq;
            bf16x8 bh = *(const bf16x8*)bp;
            bf16x8 bl = *(const bf16x8*)(bp + 61440);
            MFMA3(acc[nt],   a0h, a0l, bh, bl);
            MFMA3(acc[8+nt], a1h, a1l, bh, bl);
        }
    }

    #pragma unroll
    for (int mt = 0; mt < 2; ++mt) {
        __syncthreads();
        #pragma unroll
        for (int nt = 0; nt < 8; ++nt) {
            int col = nt*16 + ml;
            float bj = bias[col];
            #pragma unroll
            for (int r = 0; r < 4; ++r) {
                int gm = m0 + mt*16 + quad*4 + r;
                red[wv][quad*4+r][col] = gelu1(acc[mt*8+nt][r] + bj) * nbm[gm];
            }
        }
        __syncthreads();
        #pragma unroll
        for (int q = 0; q < 4; ++q) {
            int idx = lane*4 + q;
            int seg = idx >> 7, col = idx & 127;
            float s = 0.f;
            #pragma unroll
            for (int ss = 0; ss < 8; ++ss) s += red[wv][seg*8+ss][col];
            size_t orow = (size_t)(m0/8 + mt*2 + seg)*128 + col;
            short h_, l_; split2(s, h_, l_);
            nlh[orow] = h_; nll[orow] = l_;
        }
    }
}

// ---------------------------------------------------------------------------
// embed: vf = gelu((atomf[vertex]*vm)@emb + b); dual-store h0 + bf16 planes.
// ---------------------------------------------------------------------------
__global__ __launch_bounds__(256) void embed_kernel(
    const float* __restrict__ atomf, const int* __restrict__ vertex,
    const float* __restrict__ vmask,
    const short* __restrict__ WT, const float* __restrict__ bias,
    float* __restrict__ vf, float* __restrict__ h0,
    short* __restrict__ vfh, short* __restrict__ vfl)
{
    const int t = threadIdx.x;
    const int lane = t & 63, wv = t >> 6;
    const int quad = lane >> 4, ml = lane & 15;
    const int m0 = blockIdx.x*128 + wv*32;
    const int r0 = m0 + ml, r1 = m0 + 16 + ml;
    const int ga0 = vertex[r0], ga1 = vertex[r1];
    const float vm0 = vmask[r0], vm1 = vmask[r1];

    f32x4 acc[16];
    #pragma unroll
    for (int i = 0; i < 16; ++i) acc[i] = (f32x4){0.f,0.f,0.f,0.f};
    const short* wcol = WT + (size_t)ml*96;

    #pragma unroll
    for (int kc = 0; kc < 3; ++kc) {
        const int kq = kc*32 + quad*8;
        float av0[8], av1[8];
        const float* p0r = atomf + (size_t)ga0*AF + kq;
        const float* p1r = atomf + (size_t)ga1*AF + kq;
        #pragma unroll
        for (int j2 = 0; j2 < 4; ++j2) {
            int k = kq + 2*j2;
            if (k + 2 <= AF) {
                float2 v0 = *(const float2*)(p0r + 2*j2);
                float2 v1 = *(const float2*)(p1r + 2*j2);
                av0[2*j2]=v0.x*vm0; av0[2*j2+1]=v0.y*vm0;
                av1[2*j2]=v1.x*vm1; av1[2*j2+1]=v1.y*vm1;
            } else { av0[2*j2]=0.f; av0[2*j2+1]=0.f; av1[2*j2]=0.f; av1[2*j2+1]=0.f; }
        }
        bf16x8 a0h, a0l, a1h, a1l;
        #pragma unroll
        for (int j = 0; j < 8; ++j) {
            short h, l;
            split2(av0[j], h, l); a0h[j]=h; a0l[j]=l;
            split2(av1[j], h, l); a1h[j]=h; a1l[j]=l;
        }
        #pragma unroll
        for (int nt = 0; nt < 8; ++nt) {
            const short* bp = wcol + (size_t)nt*16*96 + kq;
            bf16x8 bh = *(const bf16x8*)bp;
            bf16x8 bl = *(const bf16x8*)(bp + 12288);
            MFMA3(acc[nt],   a0h, a0l, bh, bl);
            MFMA3(acc[8+nt], a1h, a1l, bh, bl);
        }
    }

    #pragma unroll
    for (int mt = 0; mt < 2; ++mt) {
        #pragma unroll
        for (int nt = 0; nt < 8; ++nt) {
            int col = nt*16 + ml;
            float bj = bias[col];
            #pragma unroll
            for (int r = 0; r < 4; ++r) {
                int gm = m0 + mt*16 + quad*4 + r;
                float v = gelu1(acc[mt*8+nt][r] + bj);
                size_t off = (size_t)gm*128 + col;
                vf[off] = v; h0[off] = v;
                short h_, l_; split2(v, h_, l_);
                vfh[off] = h_; vfl[off] = l_;
            }
        }
    }
}

// ---------------------------------------------------------------------------
// Fused master path (unchanged from round 5)
// ---------------------------------------------------------------------------
__global__ __launch_bounds__(256) void master_fused(
    const float* __restrict__ ctx, const float* __restrict__ satt,
    float* __restrict__ master,
    const float* __restrict__ wmain_w, const float* __restrict__ wmain_b,
    const float* __restrict__ khead_w, const float* __restrict__ khead_b,
    const float* __restrict__ wm2m_w,  const float* __restrict__ wm2m_b,
    const float* __restrict__ wmaster_w, const float* __restrict__ wmaster_b,
    const float* __restrict__ wzm2_w,  const float* __restrict__ wzm2_b,
    const float* __restrict__ wzs1_w,  const float* __restrict__ wzs1_b,
    const float* __restrict__ wzs2_w,  const float* __restrict__ wzs2_b,
    const float* __restrict__ WTih, const float* __restrict__ WThh,
    const float* __restrict__ bih, const float* __restrict__ bhh,
    float* __restrict__ m2m_out, float* __restrict__ t2_out)
{
    __shared__ float xs[512], ms[128];
    __shared__ float v_mtm[128], v_m2m[128], v_mself[128], v_t2[128];
    __shared__ float v_ts1[128], v_ts2[128], v_hsup[128];
    __shared__ float gi[384], gh[384];
    __shared__ float red[256];
    const int t = threadIdx.x;
    const int b = blockIdx.x;

    if (t < 128) ms[t] = master[(size_t)b*128 + t];
    __syncthreads();

    const int c = t & 127, p = t >> 7;

    #pragma unroll
    for (int k = 0; k < 4; ++k) {
        const float* cx = ctx + ((size_t)b*KK + k)*128;
        const float* Wk = wmain_w + (size_t)k*16384;
        float s = 0.f;
        for (int d = p*64; d < p*64+64; ++d) s += cx[d]*Wk[(size_t)d*128 + c];
        red[t] = s; __syncthreads();
        if (t < 128) xs[k*128 + c] = red[c] + red[c+128] + satt[(size_t)b*KK + k]*wmain_b[k*128 + c];
        __syncthreads();
    }

    auto matvec = [&](const float* src, const float* __restrict__ W,
                      const float* __restrict__ bias, int K, float* out, int act) {
        int half = K >> 1;
        int k0 = p*half, k1 = k0 + half;
        float s = 0.f;
        for (int k = k0; k < k1; ++k) s += src[k]*W[(size_t)k*128 + c];
        red[t] = s; __syncthreads();
        if (t < 128) {
            float v = red[c] + red[c+128] + bias[c];
            if (act == 1) v = gelu1(v); else if (act == 2) v = tanhf(v);
            out[c] = v;
        }
        __syncthreads();
    };

    matvec(xs, khead_w, khead_b, 512, v_mtm, 2);
    matvec(ms, wm2m_w, wm2m_b, 128, v_m2m, 1);
    matvec(ms, wmaster_w, wmaster_b, 128, v_mself, 1);
    matvec(v_m2m, wzm2_w, wzm2_b, 128, v_t2, 0);
    matvec(v_mself, wzs1_w, wzs1_b, 128, v_ts1, 0);
    matvec(v_mtm, wzs2_w, wzs2_b, 128, v_ts2, 0);

    if (t < 128) {
        float z = sig1(v_ts1[t] + v_ts2[t]);
        v_hsup[t] = (1.f-z)*v_mself[t] + z*v_mtm[t];
        m2m_out[(size_t)b*128 + t] = v_m2m[t];
        t2_out[(size_t)b*128 + t]  = v_t2[t];
    }
    __syncthreads();

    for (int j = t; j < 384; j += 256) {
        float a = 0.f, h2 = 0.f;
        for (int k = 0; k < 128; ++k) {
            a  += v_hsup[k]*WTih[(size_t)k*384 + j];
            h2 += ms[k]*WThh[(size_t)k*384 + j];
        }
        gi[j] = a + bih[j];
        gh[j] = h2 + bhh[j];
    }
    __syncthreads();
    if (t < 128) {
        float r = sig1(gi[t] + gh[t]);
        float z = sig1(gi[128+t] + gh[128+t]);
        float n = tanhf(gi[256+t] + r*gh[256+t]);
        master[(size_t)b*128 + t] = (1.f-z)*n + z*ms[t];
    }
}

// ---------------------------------------------------------------------------
// setup kernels
// ---------------------------------------------------------------------------
__global__ void wcvt_t(const float* __restrict__ src, short* __restrict__ dst,
                       int K, int Kpad, int total)
{
    int i = blockIdx.x*256 + threadIdx.x;
    if (i >= total) return;
    int z = i / (128*Kpad); int rem = i - z*128*Kpad;
    int col = rem / Kpad; int k = rem - col*Kpad;
    float v = (k < K) ? src[(size_t)z*K*128 + (size_t)k*128 + col] : 0.f;
    short h, l; split2(v, h, l);
    dst[i] = h; dst[total + i] = l;
}

__global__ void wcvt_d(const float* __restrict__ src, short* __restrict__ dst, int n)
{
    int i = blockIdx.x*256 + threadIdx.x;
    if (i < n) { short h,l; split2(src[i], h, l); dst[i]=h; dst[n+i]=l; }
}

__global__ void transpose384_kernel(const float* __restrict__ src, float* __restrict__ dst)
{
    int o = blockIdx.x*256 + threadIdx.x;
    if (o >= 49152) return;
    int k = o / 384, j = o - k*384;
    dst[o] = src[j*128 + k];
}

__global__ void e_gather_kernel(const float* __restrict__ bondf, const int* __restrict__ edge,
                                short* __restrict__ eh, short* __restrict__ el)
{
    int idx = blockIdx.x*256 + threadIdx.x;
    if (idx >= BB*EE*8) return;
    int m = idx >> 3, j = idx & 7;
    float v = (j < BF) ? bondf[edge[m]*BF + j] : 0.f;
    short h, l; split2(v, h, l);
    eh[idx] = h; el[idx] = l;
}

__global__ __launch_bounds__(256) void master_init_kernel(const float* __restrict__ vf,
                                                          const float* __restrict__ vm,
                                                          float* __restrict__ master)
{
    __shared__ float red[256];
    int b = blockIdx.x; int t = threadIdx.x; int hcol = t & 127; int half = t >> 7;
    float s = 0.f;
    for (int n = half; n < NN; n += 2)
        s += vf[((size_t)b*NN + n)*HH + hcol] * vm[b*NN + n];
    red[t] = s; __syncthreads();
    if (half == 0) master[b*HH + hcol] = red[hcol] + red[hcol + 128];
}

__global__ void copy_out_kernel(const float* __restrict__ vf, const float* __restrict__ master,
                                float* __restrict__ out)
{
    int i = blockIdx.x*256 + threadIdx.x;
    const int nvf4 = SLAB/4;
    if (i < nvf4) ((float4*)out)[i] = ((const float4*)vf)[i];
    else ((float4*)out)[i] = ((const float4*)master)[i - nvf4];
}

// ---------------------------------------------------------------------------
extern "C" void kernel_launch(void* const* d_in, const int* in_sizes, int n_in,
                              void* d_out, int out_size, void* d_ws, size_t ws_size,
                              hipStream_t stream)
{
    (void)in_sizes; (void)n_in; (void)out_size; (void)ws_size;
    const float* vmask = (const float*)d_in[1];
    const int*   vertex= (const int*)d_in[2];
    const int*   edge  = (const int*)d_in[3];
    const int*   aadj  = (const int*)d_in[4];
    const int*   badj  = (const int*)d_in[5];
    const float* nbm   = (const float*)d_in[6];
    const float* atomf = (const float*)d_in[7];
    const float* bondf = (const float*)d_in[8];
    const float* emb_w = (const float*)d_in[9];
    const float* emb_b = (const float*)d_in[10];
    const float* u1_w  = (const float*)d_in[11];
    const float* u1_b  = (const float*)d_in[12];
    const float* u2_w  = (const float*)d_in[13];
    const float* u2_b  = (const float*)d_in[14];
    const float* fu_w  = (const float*)d_in[15];
    const float* fu_b  = (const float*)d_in[16];
    const float* wvm_w = (const float*)d_in[17];
    const float* wvm_b = (const float*)d_in[18];
    const float* wmain_w=(const float*)d_in[19];
    const float* wmain_b=(const float*)d_in[20];
    const float* wbmm_w= (const float*)d_in[21];
    const float* wbmm_b= (const float*)d_in[22];
    const float* khead_w=(const float*)d_in[23];
    const float* khead_b=(const float*)d_in[24];
    const float* wmaster_w=(const float*)d_in[25];
    const float* wmaster_b=(const float*)d_in[26];
    const float* wm2m_w= (const float*)d_in[27];
    const float* wm2m_b= (const float*)d_in[28];
    const float* wzm1_w= (const float*)d_in[29];
    const float* wzm1_b= (const float*)d_in[30];
    const float* wzm2_w= (const float*)d_in[31];
    const float* wzm2_b= (const float*)d_in[32];
    const float* wzs1_w= (const float*)d_in[33];
    const float* wzs1_b= (const float*)d_in[34];
    const float* wzs2_w= (const float*)d_in[35];
    const float* wzs2_b= (const float*)d_in[36];
    const float* g_wih = (const float*)d_in[37];
    const float* g_whh = (const float*)d_in[38];
    const float* g_bih = (const float*)d_in[39];
    const float* g_bhh = (const float*)d_in[40];
    const float* gm_wih= (const float*)d_in[41];
    const float* gm_whh= (const float*)d_in[42];
    const float* gm_bih= (const float*)d_in[43];
    const float* gm_bhh= (const float*)d_in[44];

    float* ws     = (float*)d_ws;
    float* vf     = ws;
    float* h0     = vf + SLAB;
    float* score  = h0 + SLAB;
    float* ctx    = score + BB*KK*NN;
    float* satt   = ctx + BB*KK*HH;
    float* master = satt + BB*KK;
    float* m2m    = master + BB*HH;
    float* t2     = m2m + BB*HH;
    float* WTih_s = t2 + BB*HH;
    float* WThh_s = WTih_s + 128*384;
    short* vfh    = (short*)(WThh_s + 128*384);
    short* vfl    = vfh + SLAB;
    short* nlh    = vfl + SLAB;
    short* nll    = nlh + SLAB;
    short* eh     = nll + SLAB;
    short* el     = eh + BB*EE*8;
    short* wt_emb   = el + BB*EE*8;
    short* wt_wvm   = wt_emb   + 2*12288;
    short* wt_u1    = wt_wvm   + 2*196608;
    short* wt_u2    = wt_u1    + 2*61440;
    short* wt_fu    = wt_u2    + 2*98304;
    short* wt_wzm1  = wt_fu    + 2*49152;
    short* wt_gih   = wt_wzm1  + 2*49152;
    short* wt_ghh   = wt_gih   + 2*49152;

    transpose384_kernel<<<192, 256, 0, stream>>>(gm_wih, WTih_s);
    transpose384_kernel<<<192, 256, 0, stream>>>(gm_whh, WThh_s);

    wcvt_t<<<(12288+255)/256,     256, 0, stream>>>(emb_w,   wt_emb,   82, 96, 12288);
    wcvt_t<<<(196608+255)/256,    256, 0, stream>>>(wvm_w,   wt_wvm,  128,128, 196608);
    wcvt_t<<<(61440+255)/256,     256, 0, stream>>>(u1_w,    wt_u1,   134,160, 61440);
    wcvt_t<<<(98304+255)/256,     256, 0, stream>>>(u2_w,    wt_u2,   256,256, 98304);
    wcvt_t<<<(49152+255)/256,     256, 0, stream>>>(fu_w,    wt_fu,   128,128, 49152);
    wcvt_t<<<(49152+255)/256,     256, 0, stream>>>(wzm1_w,  wt_wzm1, 128,128, 49152);
    wcvt_d<<<(49152+255)/256,     256, 0, stream>>>(g_wih,   wt_gih,  49152);
    wcvt_d<<<(49152+255)/256,     256, 0, stream>>>(g_whh,   wt_ghh,  49152);

    e_gather_kernel<<<(BB*EE*8 + 255)/256, 256, 0, stream>>>(bondf, edge, eh, el);

    embed_kernel<<<256, 256, 0, stream>>>(atomf, vertex, vmask, wt_emb, emb_b,
                                          vf, h0, vfh, vfl);
    master_init_kernel<<<BB, 256, 0, stream>>>(vf, vmask, master);

    for (int i = 0; i < LL; ++i) {
        float theta = logf(0.5f/(float)(i+1) + 1.f);

        mvscore_kernel<<<256, 256, 0, stream>>>(
            vfh, vfl, wt_wvm + (size_t)i*4*16384, wvm_b + (size_t)i*4*128,
            master, wbmm_w + (size_t)i*KK*HH, wbmm_b + (size_t)i*KK, score);

        attctx_kernel<<<BB*KK, 256, 0, stream>>>(score, vmask, vf, satt, ctx);

        master_fused<<<BB, 256, 0, stream>>>(
            ctx, satt, master,
            wmain_w + (size_t)i*KK*HH*HH, wmain_b + (size_t)i*KK*HH,
            khead_w + (size_t)i*KK*HH*HH, khead_b + i*HH,
            wm2m_w + (size_t)i*HH*HH, wm2m_b + i*HH,
            wmaster_w + (size_t)i*HH*HH, wmaster_b + i*HH,
            wzm2_w + (size_t)i*HH*HH, wzm2_b + i*HH,
            wzs1_w + (size_t)i*HH*HH, wzs1_b + i*HH,
            wzs2_w + (size_t)i*HH*HH, wzs2_b + i*HH,
            WTih_s, WThh_s, gm_bih, gm_bhh,
            m2m, t2);

        u1_kernel<<<2048, 256, 0, stream>>>(
            vfh, vfl, eh, el, wt_u1 + (size_t)i*128*160, u1_b + i*HH,
            aadj, badj, nbm, nlh, nll);

        vchain<<<512, 256, 0, stream>>>(
            nlh, nll, vf, vfh, vfl, h0,
            wt_u2 + (size_t)i*128*256, u2_b + i*HH,
            wt_fu + (size_t)i*16384, fu_b + i*HH,
            wt_wzm1 + (size_t)i*16384, wzm1_b + i*HH,
            wt_gih, wt_ghh, g_bih, g_bhh,
            t2, m2m, theta);
    }

    copy_out_kernel<<<(SLAB + BB*HH)/4/256, 256, 0, stream>>>(vf, master, (float*)d_out);
}